// Round 4
// baseline (611.735 us; speedup 1.0000x reference)
//
#include <hip/hip_runtime.h>
#include <hip/hip_bf16.h>

typedef __bf16 bf16_t;
typedef __attribute__((ext_vector_type(8))) __bf16 bf16x8;
typedef __attribute__((ext_vector_type(4))) __bf16 bf16x4;
typedef __attribute__((ext_vector_type(4))) float f32x4;

#define B_ 2
#define S_ 2048
#define D_ 7168
#define R_ 1024
#define H_ 16
#define VD_ 128
#define MROWS 4096   // B_*S_
#define NQKV 2048    // fused q|kv cols
#define HVD 2048     // H_*VD_

// ---------------- async global->LDS, 16B per lane ----------------
__device__ __forceinline__ void gload_lds16(const bf16_t* g, bf16_t* l) {
    __builtin_amdgcn_global_load_lds(
        (const __attribute__((address_space(1))) unsigned int*)(g),
        (__attribute__((address_space(3))) unsigned int*)(l),
        16, 0, 0);
}

// ---------------- f32 -> bf16 conversion (optionally scaled) ----------------
__global__ __launch_bounds__(256)
void cvt_f32_bf16(const float* __restrict__ src, bf16_t* __restrict__ dst, float scale) {
    size_t i = ((size_t)blockIdx.x * 256 + threadIdx.x) * 4;
    f32x4 v = *(const f32x4*)(src + i);
    bf16x4 o;
    o[0] = (bf16_t)(v[0] * scale);
    o[1] = (bf16_t)(v[1] * scale);
    o[2] = (bf16_t)(v[2] * scale);
    o[3] = (bf16_t)(v[3] * scale);
    *(bf16x4*)(dst + i) = o;
}

// ---------------- bf16 GEMM, C = A * Bt^T  (both K-major) ----------------
// 128x128 tile, BK=64, 4 waves (2x2 of 64x64), 16x16x32 MFMA.
// Double-buffered LDS + 2-tile-deep prefetch with counted vmcnt (never 0 in
// steady state) + raw s_barrier (no compiler vmcnt(0) drain at barriers).
// LDS XOR-swizzled: element e lives at e ^ ((row(e)&7)<<3); staged via linear
// global_load_lds dest + inverse-swizzled GLOBAL source column (rule 21).
template<int OUTF32>
__global__ __launch_bounds__(256)
void gemm_bt(const bf16_t* __restrict__ A, int lda,
             const bf16_t* __restrict__ Bt, int ldb,
             void* __restrict__ Cv, int ldc,
             const float* __restrict__ bias, int K)
{
    __shared__ __align__(16) bf16_t As[2][128 * 64];
    __shared__ __align__(16) bf16_t Bs[2][128 * 64];
    const int tid  = threadIdx.x;
    const int lane = tid & 63;
    const int wave = tid >> 6;
    const int tileM = blockIdx.y * 128;
    const int tileN = blockIdx.x * 128;
    const int wr = (wave >> 1) * 64;
    const int wc = (wave & 1) * 64;
    const int r  = lane & 15;
    const int kq = lane >> 4;

    const bf16_t* Ag = A  + (size_t)tileM * lda;
    const bf16_t* Bg = Bt + (size_t)tileN * ldb;

    // per-thread staging geometry (4 x 16B for A, 4 x 16B for B per K-tile)
    int srow[4], scol[4], slin[4];
    #pragma unroll
    for (int i = 0; i < 4; ++i) {
        slin[i] = (i * 256 + tid) * 8;
        srow[i] = slin[i] >> 6;
        scol[i] = (slin[i] & 63) ^ ((srow[i] & 7) << 3);  // inverse-swizzled source
    }

    #define ISSUE_TILE(buf, k0)                                                  \
        {                                                                        \
            _Pragma("unroll")                                                    \
            for (int i = 0; i < 4; ++i) {                                        \
                gload_lds16(Ag + (size_t)srow[i] * lda + (k0) + scol[i], As[buf] + slin[i]); \
                gload_lds16(Bg + (size_t)srow[i] * ldb + (k0) + scol[i], Bs[buf] + slin[i]); \
            }                                                                    \
        }

    f32x4 acc[4][4] = {};
    const int nt = K >> 6;

    // prologue: tiles 0 and 1 in flight; wait tile 0 only (8 newest stay in flight)
    ISSUE_TILE(0, 0)
    ISSUE_TILE(1, 64)
    asm volatile("s_waitcnt vmcnt(8)" ::: "memory");
    __builtin_amdgcn_s_barrier();
    __builtin_amdgcn_sched_barrier(0);

    for (int t = 0; t < nt; ++t) {
        const int cur = t & 1;
        const bf16_t* Ab = As[cur];
        const bf16_t* Bb = Bs[cur];

        bf16x8 af[4][2], bfr[4][2];
        #pragma unroll
        for (int m = 0; m < 4; ++m)
            #pragma unroll
            for (int kk = 0; kk < 2; ++kk) {
                const int e = (wr + m * 16 + r) * 64 + kk * 32 + kq * 8;
                af[m][kk] = *(const bf16x8*)(Ab + (e ^ ((r & 7) << 3)));
            }
        #pragma unroll
        for (int n = 0; n < 4; ++n)
            #pragma unroll
            for (int kk = 0; kk < 2; ++kk) {
                const int e = (wc + n * 16 + r) * 64 + kk * 32 + kq * 8;
                bfr[n][kk] = *(const bf16x8*)(Bb + (e ^ ((r & 7) << 3)));
            }
        #pragma unroll
        for (int kk = 0; kk < 2; ++kk)
            #pragma unroll
            for (int m = 0; m < 4; ++m)
                #pragma unroll
                for (int n = 0; n < 4; ++n)
                    acc[m][n] = __builtin_amdgcn_mfma_f32_16x16x32_bf16(af[m][kk], bfr[n][kk], acc[m][n], 0, 0, 0);

        // all waves done reading buf[cur] before anyone overwrites it
        __builtin_amdgcn_s_barrier();
        __builtin_amdgcn_sched_barrier(0);
        if (t + 2 < nt) {
            ISSUE_TILE(cur, (t + 2) << 6)
            // retire tile t+1's 8 loads; keep tile t+2's 8 in flight
            asm volatile("s_waitcnt vmcnt(8)" ::: "memory");
        } else {
            asm volatile("s_waitcnt vmcnt(0)" ::: "memory");
        }
        __builtin_amdgcn_s_barrier();
        __builtin_amdgcn_sched_barrier(0);
    }
    #undef ISSUE_TILE

    // epilogue: D row=(lane>>4)*4+reg, col=lane&15
    const int orow = tileM + wr + kq * 4;
    const int ocol = tileN + wc + r;
    if (OUTF32) {
        float* C = (float*)Cv;
        #pragma unroll
        for (int n = 0; n < 4; ++n) {
            float bv = bias[ocol + n * 16];
            #pragma unroll
            for (int m = 0; m < 4; ++m)
                #pragma unroll
                for (int j = 0; j < 4; ++j)
                    C[(size_t)(orow + m * 16 + j) * ldc + ocol + n * 16] = acc[m][n][j] + bv;
        }
    } else {
        bf16_t* C = (bf16_t*)Cv;
        #pragma unroll
        for (int m = 0; m < 4; ++m)
            #pragma unroll
            for (int n = 0; n < 4; ++n)
                #pragma unroll
                for (int j = 0; j < 4; ++j)
                    C[(size_t)(orow + m * 16 + j) * ldc + ocol + n * 16] = (bf16_t)acc[m][n][j];
    }
}

// ---------------- causal flash attention in latent head space ----------------
// One wave processes one 16-row q-tile against KV tiles of 64, online softmax
// with defer-max (T13, THR=8). P staged via XOR-swizzled wave-private LDS.
__device__ __forceinline__ void attn_qtile16(
    const bf16_t* __restrict__ Q, const bf16_t* __restrict__ Kp,
    const bf16_t* __restrict__ Vp, bf16_t* __restrict__ Op,
    bf16_t* __restrict__ P_lds, int qbase, int lane)
{
    const int r  = lane & 15;
    const int kq = lane >> 4;

    // hoist Q fragments: rows qbase..qbase+15, K-dim 64 (2 k-steps)
    bf16x8 qf[2];
    #pragma unroll
    for (int kk = 0; kk < 2; ++kk)
        qf[kk] = *(const bf16x8*)(Q + (size_t)(qbase + r) * NQKV + kk * 32 + kq * 8);

    f32x4 o[8] = {};
    float mst[4], lst[4];
    #pragma unroll
    for (int j = 0; j < 4; ++j) { mst[j] = -INFINITY; lst[j] = 0.0f; }

    const int nfull  = qbase >> 6;               // tiles fully below diagonal
    const int ntiles = (qbase + 79) >> 6;        // ceil((qbase+16)/64)

    for (int t = 0; t < ntiles; ++t) {
        const int kvb = t * 64;
        // ---- scores: S = Q K^T ----
        f32x4 s[4] = {};
        #pragma unroll
        for (int n = 0; n < 4; ++n) {
            bf16x8 kf0 = *(const bf16x8*)(Kp + (size_t)(kvb + n * 16 + r) * NQKV + kq * 8);
            bf16x8 kf1 = *(const bf16x8*)(Kp + (size_t)(kvb + n * 16 + r) * NQKV + 32 + kq * 8);
            s[n] = __builtin_amdgcn_mfma_f32_16x16x32_bf16(qf[0], kf0, s[n], 0, 0, 0);
            s[n] = __builtin_amdgcn_mfma_f32_16x16x32_bf16(qf[1], kf1, s[n], 0, 0, 0);
        }
        // ---- causal mask on diagonal tiles ----
        if (t >= nfull) {
            #pragma unroll
            for (int n = 0; n < 4; ++n)
                #pragma unroll
                for (int j = 0; j < 4; ++j) {
                    int kc = kvb + n * 16 + r;
                    int qr = qbase + kq * 4 + j;
                    if (kc > qr) s[n][j] = -1e30f;
                }
        }
        // ---- batched row-max reduces (4 independent shuffle chains) ----
        float mx[4];
        #pragma unroll
        for (int j = 0; j < 4; ++j) {
            float v = fmaxf(fmaxf(s[0][j], s[1][j]), fmaxf(s[2][j], s[3][j]));
            #pragma unroll
            for (int d = 1; d < 16; d <<= 1) v = fmaxf(v, __shfl_xor(v, d, 64));
            mx[j] = v;
        }
        // ---- defer-max (T13): rescale only if some row max grew by > 8 ----
        bool need = false;
        #pragma unroll
        for (int j = 0; j < 4; ++j) need |= (mx[j] > mst[j] + 8.0f);
        if (__ballot(need)) {
            #pragma unroll
            for (int j = 0; j < 4; ++j) {
                float mnew  = fmaxf(mst[j], mx[j]);
                float alpha = __expf(mst[j] - mnew);
                lst[j] *= alpha;
                mst[j]  = mnew;
                #pragma unroll
                for (int n = 0; n < 8; ++n) o[n][j] *= alpha;
            }
        }
        // ---- P = exp(S - m), row sums, P -> swizzled LDS ----
        #pragma unroll
        for (int j = 0; j < 4; ++j) {
            float rs = 0.0f;
            const int row = kq * 4 + j;
            #pragma unroll
            for (int n = 0; n < 4; ++n) {
                float pv = __expf(s[n][j] - mst[j]);
                rs += pv;
                const int c = (n * 16 + r) ^ ((row & 7) << 3);
                P_lds[row * 64 + c] = (bf16_t)pv;
            }
            #pragma unroll
            for (int d = 1; d < 16; d <<= 1) rs += __shfl_xor(rs, d, 64);
            lst[j] += rs;
        }
        __syncthreads();
        // ---- P fragments (swizzled read) ----
        bf16x8 pf[2];
        #pragma unroll
        for (int kk = 0; kk < 2; ++kk) {
            const int e = r * 64 + kk * 32 + kq * 8;
            pf[kk] = *(const bf16x8*)(P_lds + (e ^ ((r & 7) << 3)));
        }
        // ---- O += P V  (V read K-contiguous from Vt) ----
        #pragma unroll
        for (int n = 0; n < 8; ++n) {
            #pragma unroll
            for (int kk = 0; kk < 2; ++kk) {
                bf16x8 vf = *(const bf16x8*)(Vp + (size_t)(n * 16 + r) * MROWS + kvb + kk * 32 + kq * 8);
                o[n] = __builtin_amdgcn_mfma_f32_16x16x32_bf16(pf[kk], vf, o[n], 0, 0, 0);
            }
        }
        __syncthreads();
    }

    // ---- finalize: O /= l, write bf16 ----
    #pragma unroll
    for (int j = 0; j < 4; ++j) {
        float inv = 1.0f / lst[j];
        int row = kq * 4 + j;
        #pragma unroll
        for (int n = 0; n < 8; ++n)
            Op[(size_t)(qbase + row) * HVD + n * 16 + r] = (bf16_t)(o[n][j] * inv);
    }
}

// qkv: [4096][2048] bf16 (cols 0..1023 = q_lat/SCALE, 1024..2047 = kv_lat)
// Vt:  [2048][4096] bf16, row n=h*128+vd, col m=b*2048+s
// O:   [4096][2048] bf16
// Block = 1 wave; pair-balanced: block p handles 16-row q-tiles (127-p) and p.
__global__ __launch_bounds__(64)
void attn_kernel(const bf16_t* __restrict__ qkv, const bf16_t* __restrict__ Vt,
                 bf16_t* __restrict__ O)
{
    __shared__ __align__(16) bf16_t P_lds[16 * 64];
    const int lane = threadIdx.x;
    const int p = blockIdx.x;
    const int h = blockIdx.y;
    const int b = blockIdx.z;

    const bf16_t* Q  = qkv + (size_t)(b * S_) * NQKV + h * 64;
    const bf16_t* Kp = qkv + (size_t)(b * S_) * NQKV + R_ + h * 64;
    const bf16_t* Vp = Vt + (size_t)(h * VD_) * MROWS + b * S_;
    bf16_t* Op = O + (size_t)(b * S_) * HVD + h * VD_;

    attn_qtile16(Q, Kp, Vp, Op, P_lds, (127 - p) * 16, lane);  // heavy half
    attn_qtile16(Q, Kp, Vp, Op, P_lds, p * 16, lane);          // light half
}

extern "C" void kernel_launch(void* const* d_in, const int* in_sizes, int n_in,
                              void* d_out, int out_size, void* d_ws, size_t ws_size,
                              hipStream_t stream) {
    const float* x   = (const float*)d_in[0];
    const float* Wq  = (const float*)d_in[1];
    const float* Wkv = (const float*)d_in[2];
    const float* Wvb = (const float*)d_in[3];
    const float* Wo  = (const float*)d_in[4];
    const float* bo  = (const float*)d_in[5];

    // scratch in d_out (dead before final GEMM writes it)
    char* oc = (char*)d_out;
    bf16_t* xb     = (bf16_t*)oc;                    // 4096*7168*2 = 58,720,256 B
    bf16_t* Wqkv_b = (bf16_t*)(oc + 58720256);       // 2048*7168*2 = 29,360,128 B
    // scratch in d_ws
    char* ws = (char*)d_ws;
    bf16_t* qkv_b  = (bf16_t*)ws;                    // 4096*2048*2 = 16,777,216
    bf16_t* Wvb_b  = (bf16_t*)(ws + 16777216);       // 2048*1024*2 =  4,194,304
    bf16_t* Vt_b   = (bf16_t*)(ws + 20971520);       // 2048*4096*2 = 16,777,216
    bf16_t* attn_b = (bf16_t*)(ws + 37748736);       // 4096*2048*2 = 16,777,216
    bf16_t* Wo_b   = (bf16_t*)(ws + 54525952);       // 7168*2048*2 = 29,360,128

    const float inv_scale = 0.047245559f;            // 1/sqrt(448)

    cvt_f32_bf16<<<29360128 / 1024, 256, 0, stream>>>(x,   xb, 1.0f);
    cvt_f32_bf16<<< 7340032 / 1024, 256, 0, stream>>>(Wq,  Wqkv_b, inv_scale);
    cvt_f32_bf16<<< 7340032 / 1024, 256, 0, stream>>>(Wkv, Wqkv_b + 7340032, 1.0f);
    cvt_f32_bf16<<< 2097152 / 1024, 256, 0, stream>>>(Wvb, Wvb_b, 1.0f);
    cvt_f32_bf16<<<14680064 / 1024, 256, 0, stream>>>(Wo,  Wo_b, 1.0f);

    // GEMM1: qkv_lat[4096][2048] = x @ [Wq*s | Wkv]^T   (K=7168)
    gemm_bt<0><<<dim3(16, 32), 256, 0, stream>>>(xb, D_, Wqkv_b, D_, qkv_b, NQKV, nullptr, D_);
    // GEMM2: Vt[2048][4096] = Wvb @ kv_lat^T            (K=1024)
    gemm_bt<0><<<dim3(32, 16), 256, 0, stream>>>(Wvb_b, R_, qkv_b + R_, NQKV, Vt_b, MROWS, nullptr, R_);
    // attention -> attn_b[4096][2048]  (pair-balanced grid, QBLK=16)
    attn_kernel<<<dim3(64, H_, B_), 64, 0, stream>>>(qkv_b, Vt_b, attn_b);
    // GEMM4: out[4096][7168] = attn @ Wo^T + bo         (K=2048)
    gemm_bt<1><<<dim3(56, 32), 256, 0, stream>>>(attn_b, HVD, Wo_b, HVD, d_out, D_, bo, HVD);
}

// Round 5
// 565.015 us; speedup vs baseline: 1.0827x; 1.0827x over previous
//
#include <hip/hip_runtime.h>
#include <hip/hip_bf16.h>

typedef __bf16 bf16_t;
typedef __attribute__((ext_vector_type(8))) __bf16 bf16x8;
typedef __attribute__((ext_vector_type(4))) __bf16 bf16x4;
typedef __attribute__((ext_vector_type(4))) float f32x4;

#define B_ 2
#define S_ 2048
#define D_ 7168
#define R_ 1024
#define H_ 16
#define VD_ 128
#define MROWS 4096   // B_*S_
#define NQKV 2048    // fused q|kv cols
#define HVD 2048     // H_*VD_

// ---------------- async global->LDS, 16B per lane ----------------
__device__ __forceinline__ void gload_lds16(const bf16_t* g, bf16_t* l) {
    __builtin_amdgcn_global_load_lds(
        (const __attribute__((address_space(1))) unsigned int*)(g),
        (__attribute__((address_space(3))) unsigned int*)(l),
        16, 0, 0);
}

// ---------------- f32 -> bf16 conversion (optionally scaled) ----------------
__global__ __launch_bounds__(256)
void cvt_f32_bf16(const float* __restrict__ src, bf16_t* __restrict__ dst, float scale) {
    size_t i = ((size_t)blockIdx.x * 256 + threadIdx.x) * 4;
    f32x4 v = *(const f32x4*)(src + i);
    bf16x4 o;
    o[0] = (bf16_t)(v[0] * scale);
    o[1] = (bf16_t)(v[1] * scale);
    o[2] = (bf16_t)(v[2] * scale);
    o[3] = (bf16_t)(v[3] * scale);
    *(bf16x4*)(dst + i) = o;
}

// ---------------- bf16 GEMM, C = A * Bt^T  (both K-major) ----------------
// 128x128 tile, BK=64, 4 waves (2x2 of 64x64), 16x16x32 MFMA.
// Double-buffered LDS + 2-tile-deep prefetch with counted vmcnt + raw
// s_barrier. LDS XOR-swizzled (e ^ ((row&7)<<3)); linear global_load_lds dest
// + inverse-swizzled GLOBAL source column (rule 21).
template<int OUTF32>
__global__ __launch_bounds__(256)
void gemm_bt(const bf16_t* __restrict__ A, int lda,
             const bf16_t* __restrict__ Bt, int ldb,
             void* __restrict__ Cv, int ldc,
             const float* __restrict__ bias, int K)
{
    __shared__ __align__(16) bf16_t As[2][128 * 64];
    __shared__ __align__(16) bf16_t Bs[2][128 * 64];
    const int tid  = threadIdx.x;
    const int lane = tid & 63;
    const int wave = tid >> 6;
    const int tileM = blockIdx.y * 128;
    const int tileN = blockIdx.x * 128;
    const int wr = (wave >> 1) * 64;
    const int wc = (wave & 1) * 64;
    const int r  = lane & 15;
    const int kq = lane >> 4;

    const bf16_t* Ag = A  + (size_t)tileM * lda;
    const bf16_t* Bg = Bt + (size_t)tileN * ldb;

    int srow[4], scol[4], slin[4];
    #pragma unroll
    for (int i = 0; i < 4; ++i) {
        slin[i] = (i * 256 + tid) * 8;
        srow[i] = slin[i] >> 6;
        scol[i] = (slin[i] & 63) ^ ((srow[i] & 7) << 3);  // inverse-swizzled source
    }

    #define ISSUE_TILE(buf, k0)                                                  \
        {                                                                        \
            _Pragma("unroll")                                                    \
            for (int i = 0; i < 4; ++i) {                                        \
                gload_lds16(Ag + (size_t)srow[i] * lda + (k0) + scol[i], As[buf] + slin[i]); \
                gload_lds16(Bg + (size_t)srow[i] * ldb + (k0) + scol[i], Bs[buf] + slin[i]); \
            }                                                                    \
        }

    f32x4 acc[4][4] = {};
    const int nt = K >> 6;

    ISSUE_TILE(0, 0)
    ISSUE_TILE(1, 64)
    asm volatile("s_waitcnt vmcnt(8)" ::: "memory");
    __builtin_amdgcn_s_barrier();
    __builtin_amdgcn_sched_barrier(0);

    for (int t = 0; t < nt; ++t) {
        const int cur = t & 1;
        const bf16_t* Ab = As[cur];
        const bf16_t* Bb = Bs[cur];

        bf16x8 af[4][2], bfr[4][2];
        #pragma unroll
        for (int m = 0; m < 4; ++m)
            #pragma unroll
            for (int kk = 0; kk < 2; ++kk) {
                const int e = (wr + m * 16 + r) * 64 + kk * 32 + kq * 8;
                af[m][kk] = *(const bf16x8*)(Ab + (e ^ ((r & 7) << 3)));
            }
        #pragma unroll
        for (int n = 0; n < 4; ++n)
            #pragma unroll
            for (int kk = 0; kk < 2; ++kk) {
                const int e = (wc + n * 16 + r) * 64 + kk * 32 + kq * 8;
                bfr[n][kk] = *(const bf16x8*)(Bb + (e ^ ((r & 7) << 3)));
            }
        #pragma unroll
        for (int kk = 0; kk < 2; ++kk)
            #pragma unroll
            for (int m = 0; m < 4; ++m)
                #pragma unroll
                for (int n = 0; n < 4; ++n)
                    acc[m][n] = __builtin_amdgcn_mfma_f32_16x16x32_bf16(af[m][kk], bfr[n][kk], acc[m][n], 0, 0, 0);

        __builtin_amdgcn_s_barrier();
        __builtin_amdgcn_sched_barrier(0);
        if (t + 2 < nt) {
            ISSUE_TILE(cur, (t + 2) << 6)
            asm volatile("s_waitcnt vmcnt(8)" ::: "memory");
        } else {
            asm volatile("s_waitcnt vmcnt(0)" ::: "memory");
        }
        __builtin_amdgcn_s_barrier();
        __builtin_amdgcn_sched_barrier(0);
    }
    #undef ISSUE_TILE

    const int orow = tileM + wr + kq * 4;
    const int ocol = tileN + wc + r;
    if (OUTF32) {
        float* C = (float*)Cv;
        #pragma unroll
        for (int n = 0; n < 4; ++n) {
            float bv = bias[ocol + n * 16];
            #pragma unroll
            for (int m = 0; m < 4; ++m)
                #pragma unroll
                for (int j = 0; j < 4; ++j)
                    C[(size_t)(orow + m * 16 + j) * ldc + ocol + n * 16] = acc[m][n][j] + bv;
        }
    } else {
        bf16_t* C = (bf16_t*)Cv;
        #pragma unroll
        for (int m = 0; m < 4; ++m)
            #pragma unroll
            for (int n = 0; n < 4; ++n)
                #pragma unroll
                for (int j = 0; j < 4; ++j)
                    C[(size_t)(orow + m * 16 + j) * ldc + ocol + n * 16] = (bf16_t)acc[m][n][j];
    }
}

// ---------------- causal flash attention, split-KV across 4 waves ----------------
// Block = 4 waves, one 32-row q-tile. Wave w handles KV tiles t === w (mod 4)
// (KVBLK=64), keeping private online-softmax state; block-level merge after.
// P staged in wave-private XOR-swizzled LDS (no block barriers in KV loop).
#define OPAD 132   // f32 row stride for O_acc (breaks 4-way bank aliasing)

__device__ __forceinline__ void attn_qtile32(
    const bf16_t* __restrict__ Q, const bf16_t* __restrict__ Kp,
    const bf16_t* __restrict__ Vp, bf16_t* __restrict__ Op,
    bf16_t* __restrict__ P_lds,      // wave-private 32x64
    float* __restrict__ O_acc,       // block-shared [32][OPAD]
    float* __restrict__ ml_m, float* __restrict__ ml_l,  // [4][32] each
    int qbase, int wave, int lane, int tid)
{
    const int r  = lane & 15;
    const int kq = lane >> 4;

    bf16x8 qf[2][2];
    #pragma unroll
    for (int m = 0; m < 2; ++m)
        #pragma unroll
        for (int kk = 0; kk < 2; ++kk)
            qf[m][kk] = *(const bf16x8*)(Q + (size_t)(qbase + m * 16 + r) * NQKV + kk * 32 + kq * 8);

    f32x4 o[2][8] = {};
    float mst[2][4], lst[2][4];
    #pragma unroll
    for (int m = 0; m < 2; ++m)
        #pragma unroll
        for (int j = 0; j < 4; ++j) { mst[m][j] = -INFINITY; lst[m][j] = 0.0f; }

    const int nfull  = qbase >> 6;
    const int ntiles = (qbase + 95) >> 6;

    for (int t = wave; t < ntiles; t += 4) {
        const int kvb = t * 64;
        f32x4 s[2][4] = {};
        #pragma unroll
        for (int n = 0; n < 4; ++n) {
            bf16x8 kf0 = *(const bf16x8*)(Kp + (size_t)(kvb + n * 16 + r) * NQKV + kq * 8);
            bf16x8 kf1 = *(const bf16x8*)(Kp + (size_t)(kvb + n * 16 + r) * NQKV + 32 + kq * 8);
            #pragma unroll
            for (int m = 0; m < 2; ++m) {
                s[m][n] = __builtin_amdgcn_mfma_f32_16x16x32_bf16(qf[m][0], kf0, s[m][n], 0, 0, 0);
                s[m][n] = __builtin_amdgcn_mfma_f32_16x16x32_bf16(qf[m][1], kf1, s[m][n], 0, 0, 0);
            }
        }
        if (t >= nfull) {
            #pragma unroll
            for (int m = 0; m < 2; ++m)
                #pragma unroll
                for (int n = 0; n < 4; ++n)
                    #pragma unroll
                    for (int j = 0; j < 4; ++j) {
                        int kc = kvb + n * 16 + r;
                        int qr = qbase + m * 16 + kq * 4 + j;
                        if (kc > qr) s[m][n][j] = -1e30f;
                    }
        }
        float mx[2][4];
        #pragma unroll
        for (int m = 0; m < 2; ++m)
            #pragma unroll
            for (int j = 0; j < 4; ++j) {
                float v = fmaxf(fmaxf(s[m][0][j], s[m][1][j]), fmaxf(s[m][2][j], s[m][3][j]));
                #pragma unroll
                for (int d = 1; d < 16; d <<= 1) v = fmaxf(v, __shfl_xor(v, d, 64));
                mx[m][j] = v;
            }
        bool need = false;
        #pragma unroll
        for (int m = 0; m < 2; ++m)
            #pragma unroll
            for (int j = 0; j < 4; ++j) need |= (mx[m][j] > mst[m][j] + 8.0f);
        if (__ballot(need)) {
            #pragma unroll
            for (int m = 0; m < 2; ++m)
                #pragma unroll
                for (int j = 0; j < 4; ++j) {
                    float mnew  = fmaxf(mst[m][j], mx[m][j]);
                    float alpha = __expf(mst[m][j] - mnew);
                    lst[m][j] *= alpha;
                    mst[m][j]  = mnew;
                    #pragma unroll
                    for (int n = 0; n < 8; ++n) o[m][n][j] *= alpha;
                }
        }
        #pragma unroll
        for (int m = 0; m < 2; ++m)
            #pragma unroll
            for (int j = 0; j < 4; ++j) {
                float rs = 0.0f;
                const int row = m * 16 + kq * 4 + j;
                #pragma unroll
                for (int n = 0; n < 4; ++n) {
                    float pv = __expf(s[m][n][j] - mst[m][j]);
                    rs += pv;
                    const int c = (n * 16 + r) ^ ((row & 7) << 3);
                    P_lds[row * 64 + c] = (bf16_t)pv;
                }
                #pragma unroll
                for (int d = 1; d < 16; d <<= 1) rs += __shfl_xor(rs, d, 64);
                lst[m][j] += rs;
            }
        // wave-private LDS: compiler's lgkmcnt ordering suffices, no barrier
        bf16x8 pf[2][2];
        #pragma unroll
        for (int m = 0; m < 2; ++m)
            #pragma unroll
            for (int kk = 0; kk < 2; ++kk) {
                const int e = (m * 16 + r) * 64 + kk * 32 + kq * 8;
                pf[m][kk] = *(const bf16x8*)(P_lds + (e ^ ((r & 7) << 3)));
            }
        #pragma unroll
        for (int n = 0; n < 8; ++n) {
            #pragma unroll
            for (int kk = 0; kk < 2; ++kk) {
                bf16x8 vf = *(const bf16x8*)(Vp + (size_t)(n * 16 + r) * MROWS + kvb + kk * 32 + kq * 8);
                #pragma unroll
                for (int m = 0; m < 2; ++m)
                    o[m][n] = __builtin_amdgcn_mfma_f32_16x16x32_bf16(pf[m][kk], vf, o[m][n], 0, 0, 0);
            }
        }
    }

    // ---- block-level merge of 4 partial online-softmax states ----
    if (r == 0) {
        #pragma unroll
        for (int m = 0; m < 2; ++m)
            #pragma unroll
            for (int j = 0; j < 4; ++j) {
                const int row = m * 16 + kq * 4 + j;
                ml_m[wave * 32 + row] = mst[m][j];
                ml_l[wave * 32 + row] = lst[m][j];
            }
    }
    __syncthreads();

    // per-wave rescale factor to block max
    float scl[2][4];
    #pragma unroll
    for (int m = 0; m < 2; ++m)
        #pragma unroll
        for (int j = 0; j < 4; ++j) {
            const int row = m * 16 + kq * 4 + j;
            float M = fmaxf(fmaxf(ml_m[0 * 32 + row], ml_m[1 * 32 + row]),
                            fmaxf(ml_m[2 * 32 + row], ml_m[3 * 32 + row]));
            scl[m][j] = __expf(mst[m][j] - M);   // 0 for inactive waves (mst=-inf)
        }

    // sequential accumulate rounds (wave 0 initializes)
    #pragma unroll
    for (int wq = 0; wq < 4; ++wq) {
        if (wave == wq) {
            #pragma unroll
            for (int m = 0; m < 2; ++m)
                #pragma unroll
                for (int n = 0; n < 8; ++n)
                    #pragma unroll
                    for (int j = 0; j < 4; ++j) {
                        const int row = m * 16 + kq * 4 + j;
                        const int idx = row * OPAD + n * 16 + r;
                        float v = o[m][n][j] * scl[m][j];
                        if (wq == 0) O_acc[idx] = v;
                        else         O_acc[idx] += v;
                    }
        }
        __syncthreads();
    }

    // cooperative normalized write: thread -> (row = tid>>3, 16 cols)
    {
        const int row = tid >> 3;
        const int cg  = (tid & 7) * 16;
        float M = fmaxf(fmaxf(ml_m[0 * 32 + row], ml_m[1 * 32 + row]),
                        fmaxf(ml_m[2 * 32 + row], ml_m[3 * 32 + row]));
        float lt = ml_l[0 * 32 + row] * __expf(ml_m[0 * 32 + row] - M)
                 + ml_l[1 * 32 + row] * __expf(ml_m[1 * 32 + row] - M)
                 + ml_l[2 * 32 + row] * __expf(ml_m[2 * 32 + row] - M)
                 + ml_l[3 * 32 + row] * __expf(ml_m[3 * 32 + row] - M);
        float inv = 1.0f / lt;
        bf16x8 w0, w1;
        #pragma unroll
        for (int c = 0; c < 8; ++c) {
            w0[c] = (bf16_t)(O_acc[row * OPAD + cg + c] * inv);
            w1[c] = (bf16_t)(O_acc[row * OPAD + cg + 8 + c] * inv);
        }
        *(bf16x8*)(Op + (size_t)(qbase + row) * HVD + cg)     = w0;
        *(bf16x8*)(Op + (size_t)(qbase + row) * HVD + cg + 8) = w1;
    }
    __syncthreads();   // protect O_acc/ml reuse by the next q-tile
}

// qkv: [4096][2048] bf16 (cols 0..1023 = q_lat/SCALE, 1024..2047 = kv_lat)
// Vt:  [2048][4096] bf16, row n=h*128+vd, col m=b*2048+s
// O:   [4096][2048] bf16
// Block = 4 waves (split-KV); pair-balanced: block p does q-tiles 63-p and p.
__global__ __launch_bounds__(256)
void attn_kernel(const bf16_t* __restrict__ qkv, const bf16_t* __restrict__ Vt,
                 bf16_t* __restrict__ O)
{
    __shared__ __align__(16) bf16_t P_all[4][32 * 64];
    __shared__ float O_acc[32 * OPAD];
    __shared__ float ml_m[4 * 32], ml_l[4 * 32];
    const int tid  = threadIdx.x;
    const int lane = tid & 63;
    const int wave = tid >> 6;
    const int p = blockIdx.x;
    const int h = blockIdx.y;
    const int b = blockIdx.z;

    const bf16_t* Q  = qkv + (size_t)(b * S_) * NQKV + h * 64;
    const bf16_t* Kp = qkv + (size_t)(b * S_) * NQKV + R_ + h * 64;
    const bf16_t* Vp = Vt + (size_t)(h * VD_) * MROWS + b * S_;
    bf16_t* Op = O + (size_t)(b * S_) * HVD + h * VD_;

    attn_qtile32(Q, Kp, Vp, Op, P_all[wave], O_acc, ml_m, ml_l,
                 (63 - p) * 32, wave, lane, tid);   // heavy half
    attn_qtile32(Q, Kp, Vp, Op, P_all[wave], O_acc, ml_m, ml_l,
                 p * 32, wave, lane, tid);          // light half
}

extern "C" void kernel_launch(void* const* d_in, const int* in_sizes, int n_in,
                              void* d_out, int out_size, void* d_ws, size_t ws_size,
                              hipStream_t stream) {
    const float* x   = (const float*)d_in[0];
    const float* Wq  = (const float*)d_in[1];
    const float* Wkv = (const float*)d_in[2];
    const float* Wvb = (const float*)d_in[3];
    const float* Wo  = (const float*)d_in[4];
    const float* bo  = (const float*)d_in[5];

    // scratch in d_out (dead before final GEMM writes it)
    char* oc = (char*)d_out;
    bf16_t* xb     = (bf16_t*)oc;                    // 4096*7168*2 = 58,720,256 B
    bf16_t* Wqkv_b = (bf16_t*)(oc + 58720256);       // 2048*7168*2 = 29,360,128 B
    // scratch in d_ws
    char* ws = (char*)d_ws;
    bf16_t* qkv_b  = (bf16_t*)ws;                    // 4096*2048*2 = 16,777,216
    bf16_t* Wvb_b  = (bf16_t*)(ws + 16777216);       // 2048*1024*2 =  4,194,304
    bf16_t* Vt_b   = (bf16_t*)(ws + 20971520);       // 2048*4096*2 = 16,777,216
    bf16_t* attn_b = (bf16_t*)(ws + 37748736);       // 4096*2048*2 = 16,777,216
    bf16_t* Wo_b   = (bf16_t*)(ws + 54525952);       // 7168*2048*2 = 29,360,128

    const float inv_scale = 0.047245559f;            // 1/sqrt(448)

    cvt_f32_bf16<<<29360128 / 1024, 256, 0, stream>>>(x,   xb, 1.0f);
    cvt_f32_bf16<<< 7340032 / 1024, 256, 0, stream>>>(Wq,  Wqkv_b, inv_scale);
    cvt_f32_bf16<<< 7340032 / 1024, 256, 0, stream>>>(Wkv, Wqkv_b + 7340032, 1.0f);
    cvt_f32_bf16<<< 2097152 / 1024, 256, 0, stream>>>(Wvb, Wvb_b, 1.0f);
    cvt_f32_bf16<<<14680064 / 1024, 256, 0, stream>>>(Wo,  Wo_b, 1.0f);

    // GEMM1: qkv_lat[4096][2048] = x @ [Wq*s | Wkv]^T   (K=7168)
    gemm_bt<0><<<dim3(16, 32), 256, 0, stream>>>(xb, D_, Wqkv_b, D_, qkv_b, NQKV, nullptr, D_);
    // GEMM2: Vt[2048][4096] = Wvb @ kv_lat^T            (K=1024)
    gemm_bt<0><<<dim3(32, 16), 256, 0, stream>>>(Wvb_b, R_, qkv_b + R_, NQKV, Vt_b, MROWS, nullptr, R_);
    // attention -> attn_b[4096][2048]  (split-KV, pair-balanced)
    attn_kernel<<<dim3(32, H_, B_), 256, 0, stream>>>(qkv_b, Vt_b, attn_b);
    // GEMM4: out[4096][7168] = attn @ Wo^T + bo         (K=2048)
    gemm_bt<1><<<dim3(56, 32), 256, 0, stream>>>(attn_b, HVD, Wo_b, HVD, d_out, D_, bo, HVD);
}